// Round 14
// baseline (518.816 us; speedup 1.0000x reference)
//
#include <hip/hip_runtime.h>
#include <hip/hip_bf16.h>

#define MDIM 4096
#define KDIM 4096
#define NDIM 11008

#define BM 256
#define BN 256
#define BK 128            // int8 per K-tile (two K=64 MFMA slices)
#define NT (KDIM / BK)    // 32 K-tiles

typedef int v4i __attribute__((ext_vector_type(4)));

__device__ __forceinline__ void gload_lds16(const void* g, void* s) {
  __builtin_amdgcn_global_load_lds(
      (const __attribute__((address_space(1))) void*)g,
      (__attribute__((address_space(3))) void*)s, 16, 0, 0);
}

// ---------------------------------------------------------------------------
// Kernel 1: per-token dynamic int8 quant of f32 x -> q[M,K] int8, scale[M] f32
// ---------------------------------------------------------------------------
__global__ __launch_bounds__(256) void quant_kernel(
    const float* __restrict__ x,
    unsigned* __restrict__ q,
    float* __restrict__ scales)
{
  const int row = blockIdx.x;
  const int tid = threadIdx.x;
  const float4* xr = (const float4*)(x + (size_t)row * KDIM);
  float4 v[4];
#pragma unroll
  for (int i = 0; i < 4; ++i) v[i] = xr[tid + i * 256];

  float amax = 0.f;
#pragma unroll
  for (int i = 0; i < 4; ++i) {
    amax = fmaxf(amax, fmaxf(fmaxf(fabsf(v[i].x), fabsf(v[i].y)),
                             fmaxf(fabsf(v[i].z), fabsf(v[i].w))));
  }
#pragma unroll
  for (int off = 32; off >= 1; off >>= 1)
    amax = fmaxf(amax, __shfl_xor(amax, off));
  __shared__ float red[4];
  const int lane = tid & 63, wv = tid >> 6;
  if (lane == 0) red[wv] = amax;
  __syncthreads();
  amax = fmaxf(fmaxf(red[0], red[1]), fmaxf(red[2], red[3]));

  const float scale = fmaxf(amax, 1e-7f) * (1.0f / 127.0f);
  const float rs = 1.0f / scale;
  if (tid == 0) scales[row] = scale;

#pragma unroll
  for (int i = 0; i < 4; ++i) {
    float e[4] = {v[i].x, v[i].y, v[i].z, v[i].w};
    unsigned w = 0;
#pragma unroll
    for (int j = 0; j < 4; ++j) {
      float qf = rintf(e[j] * rs);
      qf = fminf(fmaxf(qf, -128.f), 127.f);
      int qi = (int)qf;
      w |= ((unsigned)(qi & 255)) << (8 * j);
    }
    q[(size_t)row * (KDIM / 4) + tid + i * 256] = w;
  }
}

// ---------------------------------------------------------------------------
// Kernel 2: pack int32 weight [N,K] -> int8 [N,K]
// ---------------------------------------------------------------------------
__global__ __launch_bounds__(256) void pack_kernel(
    const int4* __restrict__ w32, unsigned* __restrict__ w8, int n_units)
{
  int idx = blockIdx.x * 256 + threadIdx.x;
  const int stride = gridDim.x * 256;
  for (; idx < n_units; idx += stride) {
    int4 v = w32[idx];
    unsigned d = ((unsigned)(v.x & 255)) | ((unsigned)(v.y & 255) << 8) |
                 ((unsigned)(v.z & 255) << 16) | ((unsigned)(v.w & 255) << 24);
    w8[idx] = d;
  }
}

// ---------------------------------------------------------------------------
// Kernel 3: int8 GEMM, 256x256 tile, 1024 threads = 16 waves (4M x 4N),
// per-wave 64x64. NEW vs r13: B is NOT staged in LDS — each wave loads its
// B fragments directly global->VGPR (plain compiler-visible v4i loads;
// 16 rows x 64B contiguous segments per frag-quad = fully-consumed cache
// lines; 4-way wr-wave sharing gives L1 reuse). This halves LDS-port
// traffic (was the longest pipe: B reads 128KB + writes 32KB per tile/CU)
// and removes B from barrier protection -> ONE barrier per tile, waves
// drift and self-pipeline. A stays LDS-staged via gload_lds with the
// verified conflict-free swizzle. Register discipline: af = 2 live frags,
// bf[4] reused per slice; acc 64 AGPR; cap 128 regs/wave (4 waves/SIMD).
// ---------------------------------------------------------------------------
__global__ __launch_bounds__(1024, 4) void gemm_i8_kernel(
    const signed char* __restrict__ qa,   // [M,K] int8
    const signed char* __restrict__ wb,   // [N,K] int8 (packed)
    const float* __restrict__ scales,     // [M]
    const float* __restrict__ wscale,     // [N]
    const float* __restrict__ bias,       // [N]
    float* __restrict__ out)              // [M,N] f32
{
  __shared__ __align__(16) signed char As[2][2][256 * 64];  // 64 KiB total

  const int tid = threadIdx.x;
  const int lane = tid & 63;
  const int wv = tid >> 6;       // 0..15
  const int wr = wv >> 2;        // 0..3 (M quarter)
  const int wc = wv & 3;         // 0..3 (N quarter)

  const int n0 = blockIdx.x * BN;
  const int m0 = blockIdx.y * BM;

  const signed char* Ag = qa + (size_t)m0 * KDIM;

  // per-lane B base: row = n0 + wc*64 + (lane&15), chunk = (lane>>4)*16B.
  // frag ni at tile t, slice s: + ni*16 rows + t*128 + s*64 bytes.
  const signed char* Bg =
      wb + (((size_t)(n0 + wc * 64 + (lane & 15))) << 12) + ((lane >> 4) << 4);

  // stage one 16 KiB half-tile of A (256 rows x 64 B of K-half kh), tile kt.
  // 1024 threads -> ONE gload_lds per thread. LDS dest linear; swizzle via
  // permuted GLOBAL source chunk: c_g = c_lds ^ ((r>>1)&3).
  auto stageA = [&](signed char* dst, int kt, int kh) {
    const int r = tid >> 2;                     // row 0..255
    const int cg = (tid & 3) ^ ((r >> 1) & 3);  // swizzled global chunk
    gload_lds16(Ag + (size_t)r * KDIM + (size_t)kt * BK + kh * 64 + cg * 16,
                dst + wv * 1024);
  };

  // A fragment reads (16-row pattern, measured conflict-free)
  const int swz16 = (((lane >> 4) ^ (((lane & 15) >> 1) & 3)) << 4);
  const int frow_a = wr * 64 + (lane & 15);

  auto ardA = [&](const signed char* plane, int mi) -> v4i {
    return *(const v4i*)(plane + (frow_a + mi * 16) * 64 + swz16);
  };

  v4i acc[4][4] = {};
  v4i bf[4];

  // prologue: stage A tile 0 (both K-halves)
  stageA(&As[0][0][0], 0, 0);
  stageA(&As[0][1][0], 0, 1);
  asm volatile("s_waitcnt vmcnt(0)" ::: "memory");
  __builtin_amdgcn_s_barrier();

  for (int t = 0; t < NT; ++t) {
    const int cur = t & 1;
    const int nxt = cur ^ 1;
    const bool pf = (t + 1 < NT);
    const signed char* A0 = &As[cur][0][0];
    const signed char* A1 = &As[cur][1][0];
    const size_t tb = (size_t)t * BK;

    // ----- slice 0 (kh0) -----
#pragma unroll
    for (int ni = 0; ni < 4; ++ni)
      bf[ni] = *(const v4i*)(Bg + (((size_t)ni) << 16) + tb);
    if (pf) {
      stageA(&As[nxt][0][0], t + 1, 0);
      stageA(&As[nxt][1][0], t + 1, 1);
    }
    {
      v4i a0 = ardA(A0, 0), a1 = ardA(A0, 1);
      __builtin_amdgcn_s_setprio(1);
#pragma unroll
      for (int ni = 0; ni < 4; ++ni)
        acc[0][ni] = __builtin_amdgcn_mfma_i32_16x16x64_i8(a0, bf[ni],
                                                           acc[0][ni], 0, 0, 0);
#pragma unroll
      for (int ni = 0; ni < 4; ++ni)
        acc[1][ni] = __builtin_amdgcn_mfma_i32_16x16x64_i8(a1, bf[ni],
                                                           acc[1][ni], 0, 0, 0);
      v4i a2 = ardA(A0, 2), a3 = ardA(A0, 3);
#pragma unroll
      for (int ni = 0; ni < 4; ++ni)
        acc[2][ni] = __builtin_amdgcn_mfma_i32_16x16x64_i8(a2, bf[ni],
                                                           acc[2][ni], 0, 0, 0);
#pragma unroll
      for (int ni = 0; ni < 4; ++ni)
        acc[3][ni] = __builtin_amdgcn_mfma_i32_16x16x64_i8(a3, bf[ni],
                                                           acc[3][ni], 0, 0, 0);
      __builtin_amdgcn_s_setprio(0);
    }

    // ----- slice 1 (kh1) -----
#pragma unroll
    for (int ni = 0; ni < 4; ++ni)
      bf[ni] = *(const v4i*)(Bg + (((size_t)ni) << 16) + tb + 64);
    {
      v4i a0 = ardA(A1, 0), a1 = ardA(A1, 1);
      __builtin_amdgcn_s_setprio(1);
#pragma unroll
      for (int ni = 0; ni < 4; ++ni)
        acc[0][ni] = __builtin_amdgcn_mfma_i32_16x16x64_i8(a0, bf[ni],
                                                           acc[0][ni], 0, 0, 0);
#pragma unroll
      for (int ni = 0; ni < 4; ++ni)
        acc[1][ni] = __builtin_amdgcn_mfma_i32_16x16x64_i8(a1, bf[ni],
                                                           acc[1][ni], 0, 0, 0);
      v4i a2 = ardA(A1, 2), a3 = ardA(A1, 3);
#pragma unroll
      for (int ni = 0; ni < 4; ++ni)
        acc[2][ni] = __builtin_amdgcn_mfma_i32_16x16x64_i8(a2, bf[ni],
                                                           acc[2][ni], 0, 0, 0);
#pragma unroll
      for (int ni = 0; ni < 4; ++ni)
        acc[3][ni] = __builtin_amdgcn_mfma_i32_16x16x64_i8(a3, bf[ni],
                                                           acc[3][ni], 0, 0, 0);
      __builtin_amdgcn_s_setprio(0);
    }

    // tile boundary: A stages (issued ~2000 cyc ago) must be resident
    asm volatile("s_waitcnt vmcnt(0)" ::: "memory");
    __builtin_amdgcn_s_barrier();
  }

  // epilogue: dequant + bias, f32 store (16x16 C/D: col=lane&15,
  // row=(lane>>4)*4+j — verified mapping)
  const int cl = lane & 15;
  const int rb = (lane >> 4) * 4;
#pragma unroll
  for (int ni = 0; ni < 4; ++ni) {
    const int n = n0 + wc * 64 + ni * 16 + cl;
    const float wsc = wscale[n];
    const float bs = bias[n];
#pragma unroll
    for (int mi = 0; mi < 4; ++mi) {
      const int mb = m0 + wr * 64 + mi * 16 + rb;
#pragma unroll
      for (int j = 0; j < 4; ++j) {
        const int m = mb + j;
        out[(size_t)m * NDIM + n] =
            (float)acc[mi][ni][j] * scales[m] * wsc + bs;
      }
    }
  }
}

// ---------------------------------------------------------------------------
extern "C" void kernel_launch(void* const* d_in, const int* in_sizes, int n_in,
                              void* d_out, int out_size, void* d_ws, size_t ws_size,
                              hipStream_t stream) {
  const float* x = (const float*)d_in[0];        // f32 [M,K] (fp16 upcast)
  const int* w32 = (const int*)d_in[1];          // int32 [N,K]
  const float* wscale = (const float*)d_in[2];   // [N]
  const float* bias = (const float*)d_in[3];     // [N]
  float* out = (float*)d_out;                    // f32 [M,N]

  float* scales = (float*)d_ws;                                  // 16 KB slot
  signed char* qbuf = (signed char*)d_ws + 16384;                // M*K int8
  signed char* wpack = (signed char*)d_ws + 16384 + (size_t)MDIM * KDIM;

  quant_kernel<<<MDIM, 256, 0, stream>>>(x, (unsigned*)qbuf, scales);

  const int n_units = (NDIM * KDIM) / 4;
  pack_kernel<<<2048, 256, 0, stream>>>((const int4*)w32, (unsigned*)wpack,
                                        n_units);

  dim3 grid(NDIM / BN, MDIM / BM);   // 43 x 16
  gemm_i8_kernel<<<grid, 1024, 0, stream>>>(qbuf, wpack, scales, wscale, bias,
                                            out);
}

// Round 15
// 269.229 us; speedup vs baseline: 1.9270x; 1.9270x over previous
//
#include <hip/hip_runtime.h>
#include <hip/hip_bf16.h>

#define MDIM 4096
#define KDIM 4096
#define NDIM 11008

#define BM 256
#define BN 256
#define BK 128            // int8 per K-tile (two K=64 MFMA slices)
#define NT (KDIM / BK)    // 32 K-tiles

typedef int v4i __attribute__((ext_vector_type(4)));

__device__ __forceinline__ void gload_lds16(const void* g, void* s) {
  __builtin_amdgcn_global_load_lds(
      (const __attribute__((address_space(1))) void*)g,
      (__attribute__((address_space(3))) void*)s, 16, 0, 0);
}

// ---------------------------------------------------------------------------
// Kernel 1: per-token dynamic int8 quant of f32 x -> q[M,K] int8, scale[M] f32
// ---------------------------------------------------------------------------
__global__ __launch_bounds__(256) void quant_kernel(
    const float* __restrict__ x,
    unsigned* __restrict__ q,
    float* __restrict__ scales)
{
  const int row = blockIdx.x;
  const int tid = threadIdx.x;
  const float4* xr = (const float4*)(x + (size_t)row * KDIM);
  float4 v[4];
#pragma unroll
  for (int i = 0; i < 4; ++i) v[i] = xr[tid + i * 256];

  float amax = 0.f;
#pragma unroll
  for (int i = 0; i < 4; ++i) {
    amax = fmaxf(amax, fmaxf(fmaxf(fabsf(v[i].x), fabsf(v[i].y)),
                             fmaxf(fabsf(v[i].z), fabsf(v[i].w))));
  }
#pragma unroll
  for (int off = 32; off >= 1; off >>= 1)
    amax = fmaxf(amax, __shfl_xor(amax, off));
  __shared__ float red[4];
  const int lane = tid & 63, wv = tid >> 6;
  if (lane == 0) red[wv] = amax;
  __syncthreads();
  amax = fmaxf(fmaxf(red[0], red[1]), fmaxf(red[2], red[3]));

  const float scale = fmaxf(amax, 1e-7f) * (1.0f / 127.0f);
  const float rs = 1.0f / scale;
  if (tid == 0) scales[row] = scale;

#pragma unroll
  for (int i = 0; i < 4; ++i) {
    float e[4] = {v[i].x, v[i].y, v[i].z, v[i].w};
    unsigned w = 0;
#pragma unroll
    for (int j = 0; j < 4; ++j) {
      float qf = rintf(e[j] * rs);
      qf = fminf(fmaxf(qf, -128.f), 127.f);
      int qi = (int)qf;
      w |= ((unsigned)(qi & 255)) << (8 * j);
    }
    q[(size_t)row * (KDIM / 4) + tid + i * 256] = w;
  }
}

// ---------------------------------------------------------------------------
// Kernel 2: pack int32 weight [N,K] -> int8 [N,K]
// ---------------------------------------------------------------------------
__global__ __launch_bounds__(256) void pack_kernel(
    const int4* __restrict__ w32, unsigned* __restrict__ w8, int n_units)
{
  int idx = blockIdx.x * 256 + threadIdx.x;
  const int stride = gridDim.x * 256;
  for (; idx < n_units; idx += stride) {
    int4 v = w32[idx];
    unsigned d = ((unsigned)(v.x & 255)) | ((unsigned)(v.y & 255) << 8) |
                 ((unsigned)(v.z & 255) << 16) | ((unsigned)(v.w & 255) << 24);
    w8[idx] = d;
  }
}

// ---------------------------------------------------------------------------
// Kernel 3: int8 GEMM, 256x256 tile, 1024 threads = 16 waves (4M x 4N),
// per-wave 64x64, acc[4][4] = 64 AGPR, r13 skeleton (counted vmcnt(2),
// 2 barriers/tile, conflict-free swizzle). NEW vs r13: slice-1 fragment
// reloads are software-interleaved INTO the slice-0 MFMA sequence at
// register-death points (af[mi] dead after MFMA group mi; bf after group 3).
// This feeds the LDS port during the MFMA window — breaking the CU-wide
// [read burst][MFMA burst] serialization that made wall = LDS + MFMA sum —
// at ZERO extra registers (reuse, not double-banking; 128-reg wall).
// ---------------------------------------------------------------------------
__global__ __launch_bounds__(1024, 4) void gemm_i8_kernel(
    const signed char* __restrict__ qa,   // [M,K] int8
    const signed char* __restrict__ wb,   // [N,K] int8
    const float* __restrict__ scales,     // [M]
    const float* __restrict__ wscale,     // [N]
    const float* __restrict__ bias,       // [N]
    float* __restrict__ out)              // [M,N] f32
{
  __shared__ __align__(16) signed char As[2][2][256 * 64];  // 64 KiB
  __shared__ __align__(16) signed char Bs[2][2][256 * 64];  // 64 KiB

  const int tid = threadIdx.x;
  const int lane = tid & 63;
  const int wv = tid >> 6;       // 0..15
  const int wr = wv >> 2;        // 0..3 (M quarter)
  const int wc = wv & 3;         // 0..3 (N quarter)

  const int n0 = blockIdx.x * BN;
  const int m0 = blockIdx.y * BM;

  const signed char* Ag = qa + (size_t)m0 * KDIM;
  const signed char* Bg = wb + (size_t)n0 * KDIM;

  // stage one 16 KiB half-tile (256 rows x 64 B of K-half kh) for tile kt.
  // 1024 threads -> ONE gload_lds per thread. LDS dest linear; swizzle via
  // permuted GLOBAL source chunk: c_g = c_lds ^ ((r>>1)&3).
  auto stageH = [&](signed char* dst, const signed char* g, int kt, int kh) {
    const int r = tid >> 2;                     // row 0..255
    const int cg = (tid & 3) ^ ((r >> 1) & 3);  // swizzled global chunk
    gload_lds16(g + (size_t)r * KDIM + (size_t)kt * BK + kh * 64 + cg * 16,
                dst + wv * 1024);
  };

  // fragment reads (16-row pattern, measured conflict-free)
  const int swz16 = (((lane >> 4) ^ (((lane & 15) >> 1) & 3)) << 4);
  const int frow_a = wr * 64 + (lane & 15);
  const int frow_b = wc * 64 + (lane & 15);

  auto ardA = [&](const signed char* plane, int mi) -> v4i {
    return *(const v4i*)(plane + (frow_a + mi * 16) * 64 + swz16);
  };
  auto ardB = [&](const signed char* plane, int ni) -> v4i {
    return *(const v4i*)(plane + (frow_b + ni * 16) * 64 + swz16);
  };

  v4i acc[4][4] = {};
  v4i af[4], bf[4];

  // prologue: stage tile 0 (kh0 then kh1); publish kh0, keep kh1 in flight
  stageH(&As[0][0][0], Ag, 0, 0);
  stageH(&Bs[0][0][0], Bg, 0, 0);
  stageH(&As[0][1][0], Ag, 0, 1);
  stageH(&Bs[0][1][0], Bg, 0, 1);
  asm volatile("s_waitcnt vmcnt(2)" ::: "memory");
  __builtin_amdgcn_s_barrier();

  for (int t = 0; t < NT; ++t) {
    const int cur = t & 1;
    const int nxt = cur ^ 1;
    const bool pf = (t + 1 < NT);
    const signed char* A0 = &As[cur][0][0];
    const signed char* A1 = &As[cur][1][0];
    const signed char* B0 = &Bs[cur][0][0];
    const signed char* B1 = &Bs[cur][1][0];

    // ----- slice-0 fragment reads + stage kh0(t+1) -----
#pragma unroll
    for (int mi = 0; mi < 4; ++mi) af[mi] = ardA(A0, mi);
#pragma unroll
    for (int ni = 0; ni < 4; ++ni) bf[ni] = ardB(B0, ni);
    if (pf) {
      stageH(&As[nxt][0][0], Ag, t + 1, 0);
      stageH(&Bs[nxt][0][0], Bg, t + 1, 0);
    }
    // publish kh1(t): FIFO = {kh1(t) x2, kh0(t+1) x2} -> wait to 2
    if (pf) { asm volatile("s_waitcnt vmcnt(2)" ::: "memory"); }
    else    { asm volatile("s_waitcnt vmcnt(0)" ::: "memory"); }
    __builtin_amdgcn_s_barrier();

    // ----- slice-0 MFMAs with slice-1 reloads interleaved at reg-death -----
    __builtin_amdgcn_s_setprio(1);
#pragma unroll
    for (int ni = 0; ni < 4; ++ni)
      acc[0][ni] = __builtin_amdgcn_mfma_i32_16x16x64_i8(af[0], bf[ni],
                                                         acc[0][ni], 0, 0, 0);
    af[0] = ardA(A1, 0);                 // af[0] dead -> reload slice 1
#pragma unroll
    for (int ni = 0; ni < 4; ++ni)
      acc[1][ni] = __builtin_amdgcn_mfma_i32_16x16x64_i8(af[1], bf[ni],
                                                         acc[1][ni], 0, 0, 0);
    af[1] = ardA(A1, 1);
#pragma unroll
    for (int ni = 0; ni < 4; ++ni)
      acc[2][ni] = __builtin_amdgcn_mfma_i32_16x16x64_i8(af[2], bf[ni],
                                                         acc[2][ni], 0, 0, 0);
    af[2] = ardA(A1, 2);
#pragma unroll
    for (int ni = 0; ni < 4; ++ni)
      acc[3][ni] = __builtin_amdgcn_mfma_i32_16x16x64_i8(af[3], bf[ni],
                                                         acc[3][ni], 0, 0, 0);
    af[3] = ardA(A1, 3);
#pragma unroll
    for (int ni = 0; ni < 4; ++ni) bf[ni] = ardB(B1, ni);  // bf dead now
    __builtin_amdgcn_s_setprio(0);

    // stage kh1(t+1) while slice-1 frag reads drain
    if (pf) {
      stageH(&As[nxt][1][0], Ag, t + 1, 1);
      stageH(&Bs[nxt][1][0], Bg, t + 1, 1);
    }

    // ----- slice-1 MFMAs -----
    __builtin_amdgcn_s_setprio(1);
#pragma unroll
    for (int mi = 0; mi < 4; ++mi)
#pragma unroll
      for (int ni = 0; ni < 4; ++ni)
        acc[mi][ni] = __builtin_amdgcn_mfma_i32_16x16x64_i8(
            af[mi], bf[ni], acc[mi][ni], 0, 0, 0);
    __builtin_amdgcn_s_setprio(0);
    // publish kh0(t+1): FIFO = {kh0(t+1) x2, kh1(t+1) x2} -> wait to 2
    if (pf) { asm volatile("s_waitcnt vmcnt(2)" ::: "memory"); }
    else    { asm volatile("s_waitcnt vmcnt(0)" ::: "memory"); }
    __builtin_amdgcn_s_barrier();
  }

  // epilogue: dequant + bias, f32 store (16x16 C/D: col=lane&15,
  // row=(lane>>4)*4+j — verified mapping)
  const int cl = lane & 15;
  const int rb = (lane >> 4) * 4;
#pragma unroll
  for (int ni = 0; ni < 4; ++ni) {
    const int n = n0 + wc * 64 + ni * 16 + cl;
    const float wsc = wscale[n];
    const float bs = bias[n];
#pragma unroll
    for (int mi = 0; mi < 4; ++mi) {
      const int mb = m0 + wr * 64 + mi * 16 + rb;
#pragma unroll
      for (int j = 0; j < 4; ++j) {
        const int m = mb + j;
        out[(size_t)m * NDIM + n] =
            (float)acc[mi][ni][j] * scales[m] * wsc + bs;
      }
    }
  }
}

// ---------------------------------------------------------------------------
extern "C" void kernel_launch(void* const* d_in, const int* in_sizes, int n_in,
                              void* d_out, int out_size, void* d_ws, size_t ws_size,
                              hipStream_t stream) {
  const float* x = (const float*)d_in[0];        // f32 [M,K] (fp16 upcast)
  const int* w32 = (const int*)d_in[1];          // int32 [N,K]
  const float* wscale = (const float*)d_in[2];   // [N]
  const float* bias = (const float*)d_in[3];     // [N]
  float* out = (float*)d_out;                    // f32 [M,N]

  float* scales = (float*)d_ws;                                  // 16 KB slot
  signed char* qbuf = (signed char*)d_ws + 16384;                // M*K int8
  signed char* wpack = (signed char*)d_ws + 16384 + (size_t)MDIM * KDIM;

  quant_kernel<<<MDIM, 256, 0, stream>>>(x, (unsigned*)qbuf, scales);

  const int n_units = (NDIM * KDIM) / 4;
  pack_kernel<<<2048, 256, 0, stream>>>((const int4*)w32, (unsigned*)wpack,
                                        n_units);

  dim3 grid(NDIM / BN, MDIM / BM);   // 43 x 16
  gemm_i8_kernel<<<grid, 1024, 0, stream>>>(qbuf, wpack, scales, wscale, bias,
                                            out);
}